// Round 4
// baseline (2736.730 us; speedup 1.0000x reference)
//
#include <hip/hip_runtime.h>
#include <hip/hip_bf16.h>
#include <math.h>

#define N_NODES 100000
#define N_EDGES 3200000
#define NFEAT   512
#define HIDDEN  256
#define NCLASS  64
#define K_HOPS  10
#define NTILE   4
#define TQ      25000            // source nodes per tile; 25K*128B = 3.2MB < 4MiB L2/XCD
#define NVIRT   (N_NODES * NTILE)

typedef unsigned short bfbits;
typedef __attribute__((ext_vector_type(8))) short short8x;   // 8 bf16 (4 VGPRs)
typedef __attribute__((ext_vector_type(4))) float float4x;   // MFMA C/D
typedef __attribute__((ext_vector_type(4))) float f4v;       // nt-capable float4
typedef __attribute__((ext_vector_type(2))) unsigned int u2v;// nt-capable uint2

__device__ __forceinline__ float bf2f(bfbits u) {
    union { unsigned int i; float f; } v; v.i = ((unsigned int)u) << 16; return v.f;
}
__device__ __forceinline__ bfbits f2bf(float f) {
    union { float f; unsigned int i; } v; v.f = f;
    unsigned int b = v.i + 0x7FFFu + ((v.i >> 16) & 1u);   // round-to-nearest-even
    return (bfbits)(b >> 16);
}
__device__ __forceinline__ float2 unpack2(unsigned int u) {
    float2 r;
    union { unsigned int i; float f; } a, b;
    a.i = (u & 0xFFFFu) << 16; b.i = u & 0xFFFF0000u;
    r.x = a.f; r.y = b.f; return r;
}
__device__ __forceinline__ unsigned int pack2(float x, float y) {
    return ((unsigned int)f2bf(x)) | (((unsigned int)f2bf(y)) << 16);
}

// ---------------------------------------------------------------------------
// Graph preprocessing — 4-way src-tiled CSR over 400K virtual buckets
//   vk = dst*4 + src/TQ ; self-loops handled separately in propagate pass 0
// ---------------------------------------------------------------------------

__global__ void init_kernel(int* __restrict__ bcnt, int* __restrict__ cursor, int n) {
    int i = blockIdx.x * blockDim.x + threadIdx.x;
    if (i < n) { bcnt[i] = 0; cursor[i] = 0; }
}

__global__ void count_kernel(const int* __restrict__ row, const int* __restrict__ col,
                             int* __restrict__ bcnt, int e) {
    int i = blockIdx.x * blockDim.x + threadIdx.x;
    if (i < e) {
        int r = row[i], c = col[i];
        atomicAdd(&bcnt[c * NTILE + r / TQ], 1);
    }
}

__global__ void dinv_kernel(const int* __restrict__ bcnt, float* __restrict__ dinv, int n) {
    int i = blockIdx.x * blockDim.x + threadIdx.x;
    if (i < n) {
        int d = 1 + bcnt[i * NTILE] + bcnt[i * NTILE + 1] + bcnt[i * NTILE + 2]
                  + bcnt[i * NTILE + 3];
        dinv[i] = rsqrtf((float)d);
    }
}

// --- device-wide exclusive scan of bcnt[0..n), 3 phases, 256 blocks ---
#define SCAN_NB 256
#define SCAN_NT 256

__global__ __launch_bounds__(SCAN_NT) void scan_phase1(const int* __restrict__ bcnt,
                                                       int* __restrict__ blocksums, int n) {
    int chunk = (n + SCAN_NB - 1) / SCAN_NB;
    int beg = blockIdx.x * chunk;
    int end = min(beg + chunk, n);
    int tid = threadIdx.x;
    int s = 0;
    for (int i = beg + tid; i < end; i += SCAN_NT) s += bcnt[i];
    __shared__ int wsum[SCAN_NT / 64];
#pragma unroll
    for (int o = 32; o > 0; o >>= 1) s += __shfl_xor(s, o, 64);
    if ((tid & 63) == 0) wsum[tid >> 6] = s;
    __syncthreads();
    if (tid == 0) {
        int t = 0;
#pragma unroll
        for (int w = 0; w < SCAN_NT / 64; ++w) t += wsum[w];
        blocksums[blockIdx.x] = t;
    }
}

__global__ __launch_bounds__(SCAN_NB) void scan_phase2(const int* __restrict__ blocksums,
                                                       int* __restrict__ blockbase) {
    __shared__ int t[SCAN_NB];
    int tid = threadIdx.x;
    t[tid] = blocksums[tid];
    __syncthreads();
    for (int d = 1; d < SCAN_NB; d <<= 1) {
        int v = (tid >= d) ? t[tid - d] : 0;
        __syncthreads();
        t[tid] += v;
        __syncthreads();
    }
    blockbase[tid] = (tid > 0) ? t[tid - 1] : 0;
}

__global__ __launch_bounds__(SCAN_NT) void scan_phase3(const int* __restrict__ bcnt,
                                                       const int* __restrict__ blockbase,
                                                       int* __restrict__ offs, int n) {
    __shared__ int tsum[SCAN_NT];
    int chunk = (n + SCAN_NB - 1) / SCAN_NB;
    int beg = blockIdx.x * chunk;
    int end = min(beg + chunk, n);
    int tid = threadIdx.x;
    int sub = (chunk + SCAN_NT - 1) / SCAN_NT;
    int tb = beg + tid * sub;
    int te = min(tb + sub, end);
    int s = 0;
    for (int i = tb; i < te; ++i) s += bcnt[i];
    tsum[tid] = s;
    __syncthreads();
    for (int d = 1; d < SCAN_NT; d <<= 1) {
        int v = (tid >= d) ? tsum[tid - d] : 0;
        __syncthreads();
        tsum[tid] += v;
        __syncthreads();
    }
    int run = blockbase[blockIdx.x] + ((tid > 0) ? tsum[tid - 1] : 0);
    for (int i = tb; i < te; ++i) { offs[i] = run; run += bcnt[i]; }
    if (blockIdx.x == SCAN_NB - 1 && tid == SCAN_NT - 1)
        offs[n] = blockbase[blockIdx.x] + tsum[SCAN_NT - 1];
}

// edges carry ONLY the src index (4B) — weights folded into the g-substitution
__global__ void scatter_kernel(const int* __restrict__ row, const int* __restrict__ col,
                               const int* __restrict__ offs, int* __restrict__ cursor,
                               int* __restrict__ srcs, int e) {
    int i = blockIdx.x * blockDim.x + threadIdx.x;
    if (i < e) {
        int r = row[i], c = col[i];
        int vk = c * NTILE + r / TQ;
        int p = offs[vk] + atomicAdd(&cursor[vk], 1);
        srcs[p] = r;
    }
}

// ---------------------------------------------------------------------------
// Transpose + cast fp32 [K][N] -> bf16 [N][K]
// ---------------------------------------------------------------------------
__global__ __launch_bounds__(256) void transpose_cast(const float* __restrict__ src,
                                                      bfbits* __restrict__ dst,
                                                      int K, int N) {
    __shared__ float tile[32][33];
    int kt = blockIdx.x * 32, nt = blockIdx.y * 32;
    int c = threadIdx.x & 31, r0 = threadIdx.x >> 5;
#pragma unroll
    for (int i = 0; i < 4; ++i) {
        int r = r0 + i * 8;
        tile[r][c] = src[(size_t)(kt + r) * N + nt + c];
    }
    __syncthreads();
#pragma unroll
    for (int i = 0; i < 4; ++i) {
        int r = r0 + i * 8;
        dst[(size_t)(nt + r) * K + kt + c] = f2bf(tile[c][r]);
    }
}

// ---------------------------------------------------------------------------
// GEMM1 (MFMA bf16): h_mlp = relu(x @ W1 + b1), bf16 out
// ---------------------------------------------------------------------------
#define LDP 40   // padded LDS row stride in bf16 elems

__global__ __launch_bounds__(512) void gemm1_mfma(const float* __restrict__ X,
                                                  const bfbits* __restrict__ W1T,
                                                  const float* __restrict__ bias,
                                                  bfbits* __restrict__ H, int M) {
    __shared__ short x_lds[128 * LDP];
    __shared__ short w_lds[256 * LDP];
    int tid = threadIdx.x;
    int wave = tid >> 6, lane = tid & 63;
    int l15 = lane & 15, quad = lane >> 4;
    int fslot = wave & 3, nslot = wave >> 2;
    int m0 = blockIdx.x * 128;

    float4x acc[4][4];
#pragma unroll
    for (int i = 0; i < 4; ++i)
#pragma unroll
        for (int j = 0; j < 4; ++j) acc[i][j] = (float4x){0.f, 0.f, 0.f, 0.f};

    for (int kb = 0; kb < NFEAT; kb += 32) {
#pragma unroll
        for (int c = 0; c < 2; ++c) {
            int qid = tid + c * 512;
            int node = qid >> 3;
            int k0 = (qid & 7) * 4;
            int row = m0 + node;
            float4 v = make_float4(0.f, 0.f, 0.f, 0.f);
            if (row < M) v = *reinterpret_cast<const float4*>(X + (size_t)row * NFEAT + kb + k0);
            ushort4 u;
            u.x = f2bf(v.x); u.y = f2bf(v.y); u.z = f2bf(v.z); u.w = f2bf(v.w);
            *reinterpret_cast<ushort4*>(&x_lds[node * LDP + k0]) = u;
        }
#pragma unroll
        for (int c = 0; c < 2; ++c) {
            int qid = tid + c * 512;
            int feat = qid >> 2;
            int k0 = (qid & 3) * 8;
            uint4 w = *reinterpret_cast<const uint4*>(W1T + (size_t)feat * NFEAT + kb + k0);
            *reinterpret_cast<uint4*>(&w_lds[feat * LDP + k0]) = w;
        }
        __syncthreads();
        short8x af[4], bf[4];
#pragma unroll
        for (int t = 0; t < 4; ++t) {
            af[t] = *reinterpret_cast<const short8x*>(&w_lds[(fslot * 64 + t * 16 + l15) * LDP + quad * 8]);
            bf[t] = *reinterpret_cast<const short8x*>(&x_lds[(nslot * 64 + t * 16 + l15) * LDP + quad * 8]);
        }
#pragma unroll
        for (int ft = 0; ft < 4; ++ft)
#pragma unroll
            for (int nt = 0; nt < 4; ++nt)
                acc[ft][nt] = __builtin_amdgcn_mfma_f32_16x16x32_bf16(af[ft], bf[nt], acc[ft][nt], 0, 0, 0);
        __syncthreads();
    }
#pragma unroll
    for (int ft = 0; ft < 4; ++ft) {
        int f = fslot * 64 + ft * 16 + quad * 4;
        float4 b = *reinterpret_cast<const float4*>(bias + f);
#pragma unroll
        for (int nt = 0; nt < 4; ++nt) {
            int node = m0 + nslot * 64 + nt * 16 + l15;
            if (node >= M) continue;
            float4x a = acc[ft][nt];
            ushort4 u;
            u.x = f2bf(fmaxf(a.x + b.x, 0.f));
            u.y = f2bf(fmaxf(a.y + b.y, 0.f));
            u.z = f2bf(fmaxf(a.z + b.z, 0.f));
            u.w = f2bf(fmaxf(a.w + b.w, 0.f));
            *reinterpret_cast<ushort4*>(H + (size_t)node * HIDDEN + f) = u;
        }
    }
}

// ---------------------------------------------------------------------------
// GEMM2 (MFMA bf16): v = h_mlp @ W2 + b2
//   g0 = dinv*v (bf16, [node][64] hop state);  S = (temp0/dinv)*v (fp32)
// ---------------------------------------------------------------------------
__global__ __launch_bounds__(256) void gemm2_mfma(const bfbits* __restrict__ Hm,
                                                  const bfbits* __restrict__ W2T,
                                                  const float* __restrict__ bias,
                                                  const float* __restrict__ dinv,
                                                  bfbits* __restrict__ g0,
                                                  float* __restrict__ S,
                                                  const float* __restrict__ temp, int M) {
    __shared__ short h_lds[256 * LDP];
    __shared__ short w_lds[64 * LDP];
    int tid = threadIdx.x;
    int wave = tid >> 6, lane = tid & 63;
    int l15 = lane & 15, quad = lane >> 4;
    int nslot = wave;
    int m0 = blockIdx.x * 256;

    float4x acc[4][4];
#pragma unroll
    for (int i = 0; i < 4; ++i)
#pragma unroll
        for (int j = 0; j < 4; ++j) acc[i][j] = (float4x){0.f, 0.f, 0.f, 0.f};

    for (int kb = 0; kb < HIDDEN; kb += 32) {
#pragma unroll
        for (int c = 0; c < 4; ++c) {
            int qid = tid + c * 256;
            int node = qid >> 2;
            int k0 = (qid & 3) * 8;
            int row = m0 + node;
            uint4 v = make_uint4(0u, 0u, 0u, 0u);
            if (row < M) v = *reinterpret_cast<const uint4*>(Hm + (size_t)row * HIDDEN + kb + k0);
            *reinterpret_cast<uint4*>(&h_lds[node * LDP + k0]) = v;
        }
        {
            int feat = tid >> 2;
            int k0 = (tid & 3) * 8;
            uint4 w = *reinterpret_cast<const uint4*>(W2T + (size_t)feat * HIDDEN + kb + k0);
            *reinterpret_cast<uint4*>(&w_lds[feat * LDP + k0]) = w;
        }
        __syncthreads();
        short8x af[4], bf[4];
#pragma unroll
        for (int t = 0; t < 4; ++t) {
            af[t] = *reinterpret_cast<const short8x*>(&w_lds[(t * 16 + l15) * LDP + quad * 8]);
            bf[t] = *reinterpret_cast<const short8x*>(&h_lds[(nslot * 64 + t * 16 + l15) * LDP + quad * 8]);
        }
#pragma unroll
        for (int ft = 0; ft < 4; ++ft)
#pragma unroll
            for (int nt = 0; nt < 4; ++nt)
                acc[ft][nt] = __builtin_amdgcn_mfma_f32_16x16x32_bf16(af[ft], bf[nt], acc[ft][nt], 0, 0, 0);
        __syncthreads();
    }
    float t0 = temp[0];
#pragma unroll
    for (int nt = 0; nt < 4; ++nt) {
        int node = m0 + nslot * 64 + nt * 16 + l15;
        if (node >= M) continue;
        float di = dinv[node];
        float s0 = t0 / di;
#pragma unroll
        for (int ft = 0; ft < 4; ++ft) {
            int f = ft * 16 + quad * 4;
            float4 b = *reinterpret_cast<const float4*>(bias + f);
            float4x a = acc[ft][nt];
            float4 v = make_float4(a.x + b.x, a.y + b.y, a.z + b.z, a.w + b.w);
            ushort4 u;
            u.x = f2bf(di * v.x); u.y = f2bf(di * v.y);
            u.z = f2bf(di * v.z); u.w = f2bf(di * v.w);
            *reinterpret_cast<ushort4*>(g0 + (size_t)node * NCLASS + f) = u;
            float4 sv = make_float4(s0 * v.x, s0 * v.y, s0 * v.z, s0 * v.w);
            *reinterpret_cast<float4*>(S + (size_t)node * 64 + f) = sv;
        }
    }
}

// ---------------------------------------------------------------------------
// GPR propagation, SRC-TILED multi-pass (4 passes/hop):
// Pass t gathers only from gin rows of src tile t (3.2MB slice -> L2-resident
// on every XCD by construction). Partial sums carried in fp32 A[node][64]
// (nt load/store so the stream doesn't evict the gin slice). Pass 0 adds the
// self term and init-writes A; pass 3 finalizes: gout = dinv^2*t (bf16),
// S += temp[k]*t (fp32).
// Wave per node: 4 groups x 16 lanes; group g handles edge e+g, 16 lanes read
// one 128B row coalesced. 2-deep predicated unroll (8 edges/iter).
// ---------------------------------------------------------------------------
__global__ __launch_bounds__(256) void propagate_pass(const int* __restrict__ offs2,
                                                      const int* __restrict__ srcs,
                                                      const float* __restrict__ dinv,
                                                      const uint2* __restrict__ gin,
                                                      uint2* __restrict__ gout,
                                                      float* __restrict__ A,
                                                      float* __restrict__ S,
                                                      const float* __restrict__ temp,
                                                      int kidx, int tile, int n) {
    int node = (blockIdx.x * blockDim.x + threadIdx.x) >> 6;
    int lane = threadIdx.x & 63;
    if (node >= n) return;
    int grp = lane >> 4, sub = lane & 15;
    int beg = offs2[node * NTILE + tile], end = offs2[node * NTILE + tile + 1];

    float4 acc = make_float4(0.f, 0.f, 0.f, 0.f);
    if (tile == 0 && grp == 0) {   // self term once per hop
        uint2 gs = gin[(size_t)node * 16 + sub];
        float2 lo = unpack2(gs.x), hi = unpack2(gs.y);
        acc = make_float4(lo.x, lo.y, hi.x, hi.y);
    }

    for (int e = beg; e < end; e += 8) {
        int i0 = e + grp, i1 = e + 4 + grp;
        int c0 = min(i0, end - 1), c1 = min(i1, end - 1);
        int s0 = __builtin_nontemporal_load(srcs + c0);
        int s1 = __builtin_nontemporal_load(srcs + c1);
        uint2 u0 = gin[(size_t)s0 * 16 + sub];
        uint2 u1 = gin[(size_t)s1 * 16 + sub];
        if (i0 < end) {
            float2 lo = unpack2(u0.x), hi = unpack2(u0.y);
            acc.x += lo.x; acc.y += lo.y; acc.z += hi.x; acc.w += hi.y;
        }
        if (i1 < end) {
            float2 lo = unpack2(u1.x), hi = unpack2(u1.y);
            acc.x += lo.x; acc.y += lo.y; acc.z += hi.x; acc.w += hi.y;
        }
    }

    // reduce across the 4 groups (lane bits 4,5)
    acc.x += __shfl_xor(acc.x, 16, 64); acc.y += __shfl_xor(acc.y, 16, 64);
    acc.z += __shfl_xor(acc.z, 16, 64); acc.w += __shfl_xor(acc.w, 16, 64);
    acc.x += __shfl_xor(acc.x, 32, 64); acc.y += __shfl_xor(acc.y, 32, 64);
    acc.z += __shfl_xor(acc.z, 32, 64); acc.w += __shfl_xor(acc.w, 32, 64);

    if (grp == 0) {
        f4v* Ap = (f4v*)(A + (size_t)node * 64 + sub * 4);
        if (tile == 0) {
            f4v av; av.x = acc.x; av.y = acc.y; av.z = acc.z; av.w = acc.w;
            __builtin_nontemporal_store(av, Ap);
        } else if (tile < NTILE - 1) {
            f4v a0 = __builtin_nontemporal_load(Ap);
            a0.x += acc.x; a0.y += acc.y; a0.z += acc.z; a0.w += acc.w;
            __builtin_nontemporal_store(a0, Ap);
        } else {
            f4v a0 = __builtin_nontemporal_load(Ap);
            float tx = a0.x + acc.x, ty = a0.y + acc.y;
            float tz = a0.z + acc.z, tw = a0.w + acc.w;
            float di = dinv[node];
            float dd = di * di;
            float tk = temp[kidx];
            gout[(size_t)node * 16 + sub] =
                make_uint2(pack2(dd * tx, dd * ty), pack2(dd * tz, dd * tw));
            float4* Sp = reinterpret_cast<float4*>(S + (size_t)node * 64 + sub * 4);
            float4 sv = *Sp;
            sv.x += tk * tx; sv.y += tk * ty;
            sv.z += tk * tz; sv.w += tk * tw;
            *Sp = sv;
        }
    }
}

// ---------------------------------------------------------------------------
// log_softmax over 64 classes; hidden = dinv[node] * S[node][lane]
// ---------------------------------------------------------------------------
__global__ __launch_bounds__(256) void logsoftmax_kernel(const float* __restrict__ S,
                                                         const float* __restrict__ dinv,
                                                         float* __restrict__ out, int n) {
    int node = (blockIdx.x * blockDim.x + threadIdx.x) >> 6;
    int lane = threadIdx.x & 63;
    if (node >= n) return;
    float v = dinv[node] * S[(size_t)node * 64 + lane];
    float m = v;
#pragma unroll
    for (int o = 32; o > 0; o >>= 1) m = fmaxf(m, __shfl_xor(m, o, 64));
    float ex = expf(v - m);
    float s = ex;
#pragma unroll
    for (int o = 32; o > 0; o >>= 1) s += __shfl_xor(s, o, 64);
    out[(size_t)node * 64 + lane] = v - m - logf(s);
}

// ---------------------------------------------------------------------------

extern "C" void kernel_launch(void* const* d_in, const int* in_sizes, int n_in,
                              void* d_out, int out_size, void* d_ws, size_t ws_size,
                              hipStream_t stream) {
    const float* x    = (const float*)d_in[0];
    const int*   ei   = (const int*)d_in[1];
    const int*   row  = ei;
    const int*   col  = ei + N_EDGES;
    const float* W1   = (const float*)d_in[2];
    const float* b1   = (const float*)d_in[3];
    const float* W2   = (const float*)d_in[4];
    const float* b2   = (const float*)d_in[5];
    const float* temp = (const float*)d_in[6];
    float*       out  = (float*)d_out;

    char* ws = (char*)d_ws;
    size_t off = 0;
    auto alloc = [&](size_t bytes) -> void* {
        void* p = ws + off;
        off += (bytes + 255) & ~(size_t)255;
        return p;
    };
    int*    bcnt   = (int*)   alloc((size_t)NVIRT * 4);
    int*    offs2  = (int*)   alloc((size_t)(NVIRT + 1) * 4);
    int*    cursor = (int*)   alloc((size_t)NVIRT * 4);
    float*  dinv   = (float*) alloc((size_t)N_NODES * 4);
    int*    srcs   = (int*)   alloc((size_t)N_EDGES * 4);
    int*    bsums  = (int*)   alloc((size_t)SCAN_NB * 4);
    int*    bbase  = (int*)   alloc((size_t)SCAN_NB * 4);
    bfbits* W1T    = (bfbits*)alloc((size_t)HIDDEN * NFEAT * 2);
    bfbits* W2T    = (bfbits*)alloc((size_t)NCLASS * HIDDEN * 2);
    bfbits* h_mlp  = (bfbits*)alloc((size_t)N_NODES * HIDDEN * 2);
    bfbits* g_a    = (bfbits*)alloc((size_t)N_NODES * NCLASS * 2);
    bfbits* g_b    = (bfbits*)alloc((size_t)N_NODES * NCLASS * 2);
    float*  S      = (float*) alloc((size_t)N_NODES * NCLASS * 4);
    float*  A      = (float*) alloc((size_t)N_NODES * NCLASS * 4);

    // --- graph preprocessing (4-way src-tiled CSR) ---
    init_kernel<<<(NVIRT + 255) / 256, 256, 0, stream>>>(bcnt, cursor, NVIRT);
    count_kernel<<<(N_EDGES + 255) / 256, 256, 0, stream>>>(row, col, bcnt, N_EDGES);
    dinv_kernel<<<(N_NODES + 255) / 256, 256, 0, stream>>>(bcnt, dinv, N_NODES);
    scan_phase1<<<SCAN_NB, SCAN_NT, 0, stream>>>(bcnt, bsums, NVIRT);
    scan_phase2<<<1, SCAN_NB, 0, stream>>>(bsums, bbase);
    scan_phase3<<<SCAN_NB, SCAN_NT, 0, stream>>>(bcnt, bbase, offs2, NVIRT);
    scatter_kernel<<<(N_EDGES + 255) / 256, 256, 0, stream>>>(row, col, offs2, cursor,
                                                              srcs, N_EDGES);

    // --- weight transpose+cast ---
    dim3 gt1(NFEAT / 32, HIDDEN / 32);
    transpose_cast<<<gt1, 256, 0, stream>>>(W1, W1T, NFEAT, HIDDEN);
    dim3 gt2(HIDDEN / 32, NCLASS / 32);
    transpose_cast<<<gt2, 256, 0, stream>>>(W2, W2T, HIDDEN, NCLASS);

    // --- MLP (bf16 MFMA) ---
    gemm1_mfma<<<(N_NODES + 127) / 128, 512, 0, stream>>>(x, W1T, b1, h_mlp, N_NODES);
    gemm2_mfma<<<(N_NODES + 255) / 256, 256, 0, stream>>>(h_mlp, W2T, b2, dinv, g_a, S,
                                                          temp, N_NODES);

    // --- GPR propagation: 10 hops x 4 src-tile passes ---
    int pgrid = (N_NODES * 64 + 255) / 256;
    for (int k = 0; k < K_HOPS; ++k) {
        bfbits* gi = (k & 1) ? g_b : g_a;
        bfbits* go = (k & 1) ? g_a : g_b;
        for (int t = 0; t < NTILE; ++t) {
            propagate_pass<<<pgrid, 256, 0, stream>>>(offs2, srcs, dinv,
                                                      (const uint2*)gi, (uint2*)go,
                                                      A, S, temp, k + 1, t, N_NODES);
        }
    }

    // --- log_softmax (hidden = dinv * S fused) ---
    logsoftmax_kernel<<<pgrid, 256, 0, stream>>>(S, dinv, out, N_NODES);
}

// Round 5
// 1356.519 us; speedup vs baseline: 2.0175x; 2.0175x over previous
//
#include <hip/hip_runtime.h>
#include <hip/hip_bf16.h>
#include <math.h>

#define N_NODES 100000
#define N_EDGES 3200000
#define NFEAT   512
#define HIDDEN  256
#define NCLASS  64
#define K_HOPS  10
#define NPART   8
#define PART_SZ ((N_NODES + NPART - 1) / NPART)   // 12500 dst nodes per partition

typedef unsigned short bfbits;
typedef __attribute__((ext_vector_type(8))) short short8x;   // 8 bf16 (4 VGPRs)
typedef __attribute__((ext_vector_type(4))) float float4x;   // MFMA C/D

__device__ __forceinline__ float bf2f(bfbits u) {
    union { unsigned int i; float f; } v; v.i = ((unsigned int)u) << 16; return v.f;
}
__device__ __forceinline__ bfbits f2bf(float f) {
    union { float f; unsigned int i; } v; v.f = f;
    unsigned int b = v.i + 0x7FFFu + ((v.i >> 16) & 1u);   // round-to-nearest-even
    return (bfbits)(b >> 16);
}
__device__ __forceinline__ float2 unpack2(unsigned int u) {
    float2 r;
    union { unsigned int i; float f; } a, b;
    a.i = (u & 0xFFFFu) << 16; b.i = u & 0xFFFF0000u;
    r.x = a.f; r.y = b.f; return r;
}
__device__ __forceinline__ unsigned int pack2(float x, float y) {
    return ((unsigned int)f2bf(x)) | (((unsigned int)f2bf(y)) << 16);
}

// ---------------------------------------------------------------------------
// Graph preprocessing
// ---------------------------------------------------------------------------

__global__ void init_kernel(int* __restrict__ degi, int* __restrict__ cursor, int n) {
    int i = blockIdx.x * blockDim.x + threadIdx.x;
    if (i < n) { degi[i] = 1; cursor[i] = 0; }
}

__global__ void count_kernel(const int* __restrict__ col, int* __restrict__ degi, int e) {
    int i = blockIdx.x * blockDim.x + threadIdx.x;
    if (i < e) atomicAdd(&degi[col[i]], 1);
}

__global__ void dinv_kernel(const int* __restrict__ degi, float* __restrict__ dinv, int n) {
    int i = blockIdx.x * blockDim.x + threadIdx.x;
    if (i < n) dinv[i] = rsqrtf((float)degi[i]);
}

// --- device-wide exclusive scan of (degi[i]-1), 3 phases, 256 blocks ---
#define SCAN_NB 256
#define SCAN_NT 256

__global__ __launch_bounds__(SCAN_NT) void scan_phase1(const int* __restrict__ degi,
                                                       int* __restrict__ blocksums, int n) {
    int chunk = (n + SCAN_NB - 1) / SCAN_NB;
    int beg = blockIdx.x * chunk;
    int end = min(beg + chunk, n);
    int tid = threadIdx.x;
    int s = 0;
    for (int i = beg + tid; i < end; i += SCAN_NT) s += degi[i] - 1;
    __shared__ int wsum[SCAN_NT / 64];
#pragma unroll
    for (int o = 32; o > 0; o >>= 1) s += __shfl_xor(s, o, 64);
    if ((tid & 63) == 0) wsum[tid >> 6] = s;
    __syncthreads();
    if (tid == 0) {
        int t = 0;
#pragma unroll
        for (int w = 0; w < SCAN_NT / 64; ++w) t += wsum[w];
        blocksums[blockIdx.x] = t;
    }
}

__global__ __launch_bounds__(SCAN_NB) void scan_phase2(const int* __restrict__ blocksums,
                                                       int* __restrict__ blockbase) {
    __shared__ int t[SCAN_NB];
    int tid = threadIdx.x;
    t[tid] = blocksums[tid];
    __syncthreads();
    for (int d = 1; d < SCAN_NB; d <<= 1) {
        int v = (tid >= d) ? t[tid - d] : 0;
        __syncthreads();
        t[tid] += v;
        __syncthreads();
    }
    blockbase[tid] = (tid > 0) ? t[tid - 1] : 0;
}

__global__ __launch_bounds__(SCAN_NT) void scan_phase3(const int* __restrict__ degi,
                                                       const int* __restrict__ blockbase,
                                                       int* __restrict__ offs, int n) {
    __shared__ int tsum[SCAN_NT];
    int chunk = (n + SCAN_NB - 1) / SCAN_NB;
    int beg = blockIdx.x * chunk;
    int end = min(beg + chunk, n);
    int tid = threadIdx.x;
    int sub = (chunk + SCAN_NT - 1) / SCAN_NT;
    int tb = beg + tid * sub;
    int te = min(tb + sub, end);
    int s = 0;
    for (int i = tb; i < te; ++i) s += degi[i] - 1;
    tsum[tid] = s;
    __syncthreads();
    for (int d = 1; d < SCAN_NT; d <<= 1) {
        int v = (tid >= d) ? tsum[tid - d] : 0;
        __syncthreads();
        tsum[tid] += v;
        __syncthreads();
    }
    int run = blockbase[blockIdx.x] + ((tid > 0) ? tsum[tid - 1] : 0);
    for (int i = tb; i < te; ++i) { offs[i] = run; run += degi[i] - 1; }
    if (blockIdx.x == SCAN_NB - 1 && tid == SCAN_NT - 1)
        offs[n] = blockbase[blockIdx.x] + tsum[SCAN_NT - 1];
}

// ---------------------------------------------------------------------------
// Partitioned scatter: part g = blockIdx&7 (maps to XCD g under round-robin
// dispatch) handles only edges with dst in [g*PART_SZ, (g+1)*PART_SZ).
// Each part's srcs writes land in ONE contiguous ~1.6MB CSR region -> lines
// go fully dirty inside one L2 before eviction (write amp ~1x vs ~16x), and
// cursor atomics become part-local. Cost: col/row re-read once per part
// (coalesced, L3-resident).
// ---------------------------------------------------------------------------
__global__ __launch_bounds__(256) void scatter_part(const int* __restrict__ row,
                                                    const int* __restrict__ col,
                                                    const int* __restrict__ offs,
                                                    int* __restrict__ cursor,
                                                    int* __restrict__ srcs, int e) {
    int part = blockIdx.x & (NPART - 1);
    int blk  = blockIdx.x >> 3;
    int nthr = (gridDim.x >> 3) * blockDim.x;
    int lo = part * PART_SZ, hi = lo + PART_SZ;
    for (int i = blk * blockDim.x + threadIdx.x; i < e; i += nthr) {
        int c = col[i];
        int r = row[i];
        if (c >= lo && c < hi) {
            int p = offs[c] + atomicAdd(&cursor[c], 1);
            srcs[p] = r;
        }
    }
}

// ---------------------------------------------------------------------------
// Transpose + cast fp32 [K][N] -> bf16 [N][K]
// ---------------------------------------------------------------------------
__global__ __launch_bounds__(256) void transpose_cast(const float* __restrict__ src,
                                                      bfbits* __restrict__ dst,
                                                      int K, int N) {
    __shared__ float tile[32][33];
    int kt = blockIdx.x * 32, nt = blockIdx.y * 32;
    int c = threadIdx.x & 31, r0 = threadIdx.x >> 5;
#pragma unroll
    for (int i = 0; i < 4; ++i) {
        int r = r0 + i * 8;
        tile[r][c] = src[(size_t)(kt + r) * N + nt + c];
    }
    __syncthreads();
#pragma unroll
    for (int i = 0; i < 4; ++i) {
        int r = r0 + i * 8;
        dst[(size_t)(nt + r) * K + kt + c] = f2bf(tile[c][r]);
    }
}

// ---------------------------------------------------------------------------
// GEMM1 (MFMA bf16): h_mlp = relu(x @ W1 + b1), bf16 out
// ---------------------------------------------------------------------------
#define LDP 40   // padded LDS row stride in bf16 elems

__global__ __launch_bounds__(512) void gemm1_mfma(const float* __restrict__ X,
                                                  const bfbits* __restrict__ W1T,
                                                  const float* __restrict__ bias,
                                                  bfbits* __restrict__ H, int M) {
    __shared__ short x_lds[128 * LDP];
    __shared__ short w_lds[256 * LDP];
    int tid = threadIdx.x;
    int wave = tid >> 6, lane = tid & 63;
    int l15 = lane & 15, quad = lane >> 4;
    int fslot = wave & 3, nslot = wave >> 2;
    int m0 = blockIdx.x * 128;

    float4x acc[4][4];
#pragma unroll
    for (int i = 0; i < 4; ++i)
#pragma unroll
        for (int j = 0; j < 4; ++j) acc[i][j] = (float4x){0.f, 0.f, 0.f, 0.f};

    for (int kb = 0; kb < NFEAT; kb += 32) {
#pragma unroll
        for (int c = 0; c < 2; ++c) {
            int qid = tid + c * 512;
            int node = qid >> 3;
            int k0 = (qid & 7) * 4;
            int row = m0 + node;
            float4 v = make_float4(0.f, 0.f, 0.f, 0.f);
            if (row < M) v = *reinterpret_cast<const float4*>(X + (size_t)row * NFEAT + kb + k0);
            ushort4 u;
            u.x = f2bf(v.x); u.y = f2bf(v.y); u.z = f2bf(v.z); u.w = f2bf(v.w);
            *reinterpret_cast<ushort4*>(&x_lds[node * LDP + k0]) = u;
        }
#pragma unroll
        for (int c = 0; c < 2; ++c) {
            int qid = tid + c * 512;
            int feat = qid >> 2;
            int k0 = (qid & 3) * 8;
            uint4 w = *reinterpret_cast<const uint4*>(W1T + (size_t)feat * NFEAT + kb + k0);
            *reinterpret_cast<uint4*>(&w_lds[feat * LDP + k0]) = w;
        }
        __syncthreads();
        short8x af[4], bf[4];
#pragma unroll
        for (int t = 0; t < 4; ++t) {
            af[t] = *reinterpret_cast<const short8x*>(&w_lds[(fslot * 64 + t * 16 + l15) * LDP + quad * 8]);
            bf[t] = *reinterpret_cast<const short8x*>(&x_lds[(nslot * 64 + t * 16 + l15) * LDP + quad * 8]);
        }
#pragma unroll
        for (int ft = 0; ft < 4; ++ft)
#pragma unroll
            for (int nt = 0; nt < 4; ++nt)
                acc[ft][nt] = __builtin_amdgcn_mfma_f32_16x16x32_bf16(af[ft], bf[nt], acc[ft][nt], 0, 0, 0);
        __syncthreads();
    }
#pragma unroll
    for (int ft = 0; ft < 4; ++ft) {
        int f = fslot * 64 + ft * 16 + quad * 4;
        float4 b = *reinterpret_cast<const float4*>(bias + f);
#pragma unroll
        for (int nt = 0; nt < 4; ++nt) {
            int node = m0 + nslot * 64 + nt * 16 + l15;
            if (node >= M) continue;
            float4x a = acc[ft][nt];
            ushort4 u;
            u.x = f2bf(fmaxf(a.x + b.x, 0.f));
            u.y = f2bf(fmaxf(a.y + b.y, 0.f));
            u.z = f2bf(fmaxf(a.z + b.z, 0.f));
            u.w = f2bf(fmaxf(a.w + b.w, 0.f));
            *reinterpret_cast<ushort4*>(H + (size_t)node * HIDDEN + f) = u;
        }
    }
}

// ---------------------------------------------------------------------------
// GEMM2 (MFMA bf16): v = h_mlp @ W2 + b2
//   g0 = dinv*v (bf16, hop state);  S = (temp0/dinv)*v (fp32 accumulator)
// Final output will be dinv * S (fused into logsoftmax).
// ---------------------------------------------------------------------------
__global__ __launch_bounds__(256) void gemm2_mfma(const bfbits* __restrict__ Hm,
                                                  const bfbits* __restrict__ W2T,
                                                  const float* __restrict__ bias,
                                                  const float* __restrict__ dinv,
                                                  bfbits* __restrict__ g0,
                                                  float* __restrict__ S,
                                                  const float* __restrict__ temp, int M) {
    __shared__ short h_lds[256 * LDP];
    __shared__ short w_lds[64 * LDP];
    int tid = threadIdx.x;
    int wave = tid >> 6, lane = tid & 63;
    int l15 = lane & 15, quad = lane >> 4;
    int nslot = wave;
    int m0 = blockIdx.x * 256;

    float4x acc[4][4];
#pragma unroll
    for (int i = 0; i < 4; ++i)
#pragma unroll
        for (int j = 0; j < 4; ++j) acc[i][j] = (float4x){0.f, 0.f, 0.f, 0.f};

    for (int kb = 0; kb < HIDDEN; kb += 32) {
#pragma unroll
        for (int c = 0; c < 4; ++c) {
            int qid = tid + c * 256;
            int node = qid >> 2;
            int k0 = (qid & 3) * 8;
            int row = m0 + node;
            uint4 v = make_uint4(0u, 0u, 0u, 0u);
            if (row < M) v = *reinterpret_cast<const uint4*>(Hm + (size_t)row * HIDDEN + kb + k0);
            *reinterpret_cast<uint4*>(&h_lds[node * LDP + k0]) = v;
        }
        {
            int feat = tid >> 2;
            int k0 = (tid & 3) * 8;
            uint4 w = *reinterpret_cast<const uint4*>(W2T + (size_t)feat * HIDDEN + kb + k0);
            *reinterpret_cast<uint4*>(&w_lds[feat * LDP + k0]) = w;
        }
        __syncthreads();
        short8x af[4], bf[4];
#pragma unroll
        for (int t = 0; t < 4; ++t) {
            af[t] = *reinterpret_cast<const short8x*>(&w_lds[(t * 16 + l15) * LDP + quad * 8]);
            bf[t] = *reinterpret_cast<const short8x*>(&h_lds[(nslot * 64 + t * 16 + l15) * LDP + quad * 8]);
        }
#pragma unroll
        for (int ft = 0; ft < 4; ++ft)
#pragma unroll
            for (int nt = 0; nt < 4; ++nt)
                acc[ft][nt] = __builtin_amdgcn_mfma_f32_16x16x32_bf16(af[ft], bf[nt], acc[ft][nt], 0, 0, 0);
        __syncthreads();
    }
    float t0 = temp[0];
#pragma unroll
    for (int nt = 0; nt < 4; ++nt) {
        int node = m0 + nslot * 64 + nt * 16 + l15;
        if (node >= M) continue;
        float di = dinv[node];
        float s0 = t0 / di;
#pragma unroll
        for (int ft = 0; ft < 4; ++ft) {
            int f = ft * 16 + quad * 4;
            float4 b = *reinterpret_cast<const float4*>(bias + f);
            float4x a = acc[ft][nt];
            float4 v = make_float4(a.x + b.x, a.y + b.y, a.z + b.z, a.w + b.w);
            ushort4 u;
            u.x = f2bf(di * v.x); u.y = f2bf(di * v.y);
            u.z = f2bf(di * v.z); u.w = f2bf(di * v.w);
            *reinterpret_cast<ushort4*>(g0 + (size_t)node * NCLASS + f) = u;
            float4 sv = make_float4(s0 * v.x, s0 * v.y, s0 * v.z, s0 * v.w);
            *reinterpret_cast<float4*>(S + (size_t)node * 64 + f) = sv;
        }
    }
}

// ---------------------------------------------------------------------------
// GPR propagation (g-form): t[c] = g[c] + sum_{r->c} g[r]   (pure sum!)
//   g_out[c] = dinv[c]^2 * t[c]   (bf16);   S[c] += temp[k] * t[c]  (fp32)
// Wave per node; quarter-wave (16 lanes, uint2 = 4 bf16 feats) per edge:
// one gather instruction covers 4 edges (512B). Unroll 16 edges.
// (Round-1 form — best measured; r2/r3/r4 variants all regressed.)
// ---------------------------------------------------------------------------
__global__ __launch_bounds__(256) void propagate_kernel(const int* __restrict__ offs,
                                                        const int* __restrict__ srcs,
                                                        const float* __restrict__ dinv,
                                                        const uint2* __restrict__ gin,
                                                        uint2* __restrict__ gout,
                                                        float* __restrict__ S,
                                                        const float* __restrict__ temp,
                                                        int kidx, int n) {
    int node = (blockIdx.x * blockDim.x + threadIdx.x) >> 6;
    int lane = threadIdx.x & 63;
    if (node >= n) return;
    int q = lane >> 4, sub = lane & 15;
    float tk = temp[kidx];
    int beg = offs[node], end = offs[node + 1];

    // self term on quarter 0
    uint2 gs = gin[(size_t)node * 16 + sub];
    float4 acc = make_float4(0.f, 0.f, 0.f, 0.f);
    if (q == 0) {
        float2 lo = unpack2(gs.x), hi = unpack2(gs.y);
        acc = make_float4(lo.x, lo.y, hi.x, hi.y);
    }

    int e = beg;
    for (; e + 16 <= end; e += 16) {
#pragma unroll
        for (int j = 0; j < 4; ++j) {
            int s = srcs[e + j * 4 + q];
            uint2 u = gin[(size_t)s * 16 + sub];
            float2 lo = unpack2(u.x), hi = unpack2(u.y);
            acc.x += lo.x; acc.y += lo.y; acc.z += hi.x; acc.w += hi.y;
        }
    }
    for (; e < end; e += 4) {
        int idx = e + q;
        int sidx = (idx < end) ? idx : e;
        int s = srcs[sidx];
        uint2 u = gin[(size_t)s * 16 + sub];
        if (idx < end) {
            float2 lo = unpack2(u.x), hi = unpack2(u.y);
            acc.x += lo.x; acc.y += lo.y; acc.z += hi.x; acc.w += hi.y;
        }
    }

    // reduce across the 4 quarter-waves
    acc.x += __shfl_xor(acc.x, 16, 64); acc.y += __shfl_xor(acc.y, 16, 64);
    acc.z += __shfl_xor(acc.z, 16, 64); acc.w += __shfl_xor(acc.w, 16, 64);
    acc.x += __shfl_xor(acc.x, 32, 64); acc.y += __shfl_xor(acc.y, 32, 64);
    acc.z += __shfl_xor(acc.z, 32, 64); acc.w += __shfl_xor(acc.w, 32, 64);

    if (q == 0) {
        float di = dinv[node];
        float dd = di * di;
        gout[(size_t)node * 16 + sub] =
            make_uint2(pack2(dd * acc.x, dd * acc.y), pack2(dd * acc.z, dd * acc.w));
        float4* Sp = reinterpret_cast<float4*>(S + (size_t)node * 64 + sub * 4);
        float4 sv = *Sp;
        sv.x += tk * acc.x; sv.y += tk * acc.y;
        sv.z += tk * acc.z; sv.w += tk * acc.w;
        *Sp = sv;
    }
}

// ---------------------------------------------------------------------------
// log_softmax over 64 classes; hidden = dinv[node] * S[node][lane]
// ---------------------------------------------------------------------------
__global__ __launch_bounds__(256) void logsoftmax_kernel(const float* __restrict__ S,
                                                         const float* __restrict__ dinv,
                                                         float* __restrict__ out, int n) {
    int node = (blockIdx.x * blockDim.x + threadIdx.x) >> 6;
    int lane = threadIdx.x & 63;
    if (node >= n) return;
    float v = dinv[node] * S[(size_t)node * 64 + lane];
    float m = v;
#pragma unroll
    for (int o = 32; o > 0; o >>= 1) m = fmaxf(m, __shfl_xor(m, o, 64));
    float ex = expf(v - m);
    float s = ex;
#pragma unroll
    for (int o = 32; o > 0; o >>= 1) s += __shfl_xor(s, o, 64);
    out[(size_t)node * 64 + lane] = v - m - logf(s);
}

// ---------------------------------------------------------------------------

extern "C" void kernel_launch(void* const* d_in, const int* in_sizes, int n_in,
                              void* d_out, int out_size, void* d_ws, size_t ws_size,
                              hipStream_t stream) {
    const float* x    = (const float*)d_in[0];
    const int*   ei   = (const int*)d_in[1];
    const int*   row  = ei;
    const int*   col  = ei + N_EDGES;
    const float* W1   = (const float*)d_in[2];
    const float* b1   = (const float*)d_in[3];
    const float* W2   = (const float*)d_in[4];
    const float* b2   = (const float*)d_in[5];
    const float* temp = (const float*)d_in[6];
    float*       out  = (float*)d_out;

    char* ws = (char*)d_ws;
    size_t off = 0;
    auto alloc = [&](size_t bytes) -> void* {
        void* p = ws + off;
        off += (bytes + 255) & ~(size_t)255;
        return p;
    };
    int*    degi   = (int*)   alloc((size_t)N_NODES * 4);
    float*  dinv   = (float*) alloc((size_t)N_NODES * 4);
    int*    offs   = (int*)   alloc((size_t)(N_NODES + 1) * 4);
    int*    cursor = (int*)   alloc((size_t)N_NODES * 4);
    int*    srcs   = (int*)   alloc((size_t)N_EDGES * 4);
    int*    bsums  = (int*)   alloc((size_t)SCAN_NB * 4);
    int*    bbase  = (int*)   alloc((size_t)SCAN_NB * 4);
    bfbits* W1T    = (bfbits*)alloc((size_t)HIDDEN * NFEAT * 2);
    bfbits* W2T    = (bfbits*)alloc((size_t)NCLASS * HIDDEN * 2);
    bfbits* h_mlp  = (bfbits*)alloc((size_t)N_NODES * HIDDEN * 2);
    bfbits* g_a    = (bfbits*)alloc((size_t)N_NODES * NCLASS * 2);
    bfbits* g_b    = (bfbits*)alloc((size_t)N_NODES * NCLASS * 2);
    float*  S      = (float*) alloc((size_t)N_NODES * NCLASS * 4);

    // --- graph preprocessing ---
    init_kernel<<<(N_NODES + 255) / 256, 256, 0, stream>>>(degi, cursor, N_NODES);
    count_kernel<<<(N_EDGES + 255) / 256, 256, 0, stream>>>(col, degi, N_EDGES);
    dinv_kernel<<<(N_NODES + 255) / 256, 256, 0, stream>>>(degi, dinv, N_NODES);
    scan_phase1<<<SCAN_NB, SCAN_NT, 0, stream>>>(degi, bsums, N_NODES);
    scan_phase2<<<1, SCAN_NB, 0, stream>>>(bsums, bbase);
    scan_phase3<<<SCAN_NB, SCAN_NT, 0, stream>>>(degi, bbase, offs, N_NODES);
    scatter_part<<<2048, 256, 0, stream>>>(row, col, offs, cursor, srcs, N_EDGES);

    // --- weight transpose+cast ---
    dim3 gt1(NFEAT / 32, HIDDEN / 32);
    transpose_cast<<<gt1, 256, 0, stream>>>(W1, W1T, NFEAT, HIDDEN);
    dim3 gt2(HIDDEN / 32, NCLASS / 32);
    transpose_cast<<<gt2, 256, 0, stream>>>(W2, W2T, HIDDEN, NCLASS);

    // --- MLP (bf16 MFMA) ---
    gemm1_mfma<<<(N_NODES + 127) / 128, 512, 0, stream>>>(x, W1T, b1, h_mlp, N_NODES);
    gemm2_mfma<<<(N_NODES + 255) / 256, 256, 0, stream>>>(h_mlp, W2T, b2, dinv, g_a, S,
                                                          temp, N_NODES);

    // --- GPR propagation: 10 hops ---
    int pgrid = (N_NODES * 64 + 255) / 256;
    for (int k = 0; k < K_HOPS; ++k) {
        bfbits* gi = (k & 1) ? g_b : g_a;
        bfbits* go = (k & 1) ? g_a : g_b;
        propagate_kernel<<<pgrid, 256, 0, stream>>>(offs, srcs, dinv,
                                                    (const uint2*)gi, (uint2*)go, S,
                                                    temp, k + 1, N_NODES);
    }

    // --- log_softmax (hidden = dinv * S fused) ---
    logsoftmax_kernel<<<pgrid, 256, 0, stream>>>(S, dinv, out, N_NODES);
}